// Round 1
// 315.278 us; speedup vs baseline: 1.0602x; 1.0602x over previous
//
#include <hip/hip_runtime.h>

#define NN 2048
#define SEG 32              // elements per lane (one 128-B line)
#define WPB 4               // waves per block (256 threads)
#define ROWS_PER_WAVE 4

// One WAVE per row. The Givens chain
//   a_k = c_k*x[k] - s_k*a_{k+1},  y[k+1] = s_k*x[k] + c_k*a_{k+1}
// is affine in the carry -> parallelize with a 64-lane suffix scan of
// (U, M) maps, where segment map:  a_out = U + M*a_in,
// compose(A,B)(a) = A(B(a)) = (U_A + M_A*U_B, M_A*M_B).
// Ring boundary folds in uniformly:
//   carry entering k=2047 is x[0];  element k=0 uses t0 = s_2047*x[2047]+c_2047*x[0];
//   y[0] = final carry out of lane 0.
__global__ __launch_bounds__(256, 4) void ring_givens_scan_kernel(
        const float* __restrict__ x,
        const float* __restrict__ angles,
        float* __restrict__ y,
        int B) {
    const int lane  = threadIdx.x & 63;
    const int wib   = threadIdx.x >> 6;
    const int gwid  = blockIdx.x * WPB + wib;
    const int total_waves = gridDim.x * WPB;

    // --- per-lane (c,s) table for k in [lane*32, lane*32+31], once per block-life ---
    float c[SEG], s[SEG];
    {
        const float* ap = angles + lane * SEG;
        #pragma unroll
        for (int j = 0; j < SEG; j += 4) {
            float4 av = *(const float4*)(ap + j);
            sincosf(av.x, &s[j    ], &c[j    ]);
            sincosf(av.y, &s[j + 1], &c[j + 1]);
            sincosf(av.z, &s[j + 2], &c[j + 2]);
            sincosf(av.w, &s[j + 3], &c[j + 3]);
        }
    }
    float sl, cl;                     // cs[NN-1], needed by lane 0 for t0
    sincosf(angles[NN - 1], &sl, &cl);

    for (int r = 0; r < ROWS_PER_WAVE; ++r) {
        const int row = gwid + r * total_waves;
        if (row >= B) break;
        const float* __restrict__ xr = x + (size_t)row * NN;
        float*       __restrict__ yr = y + (size_t)row * NN;

        // --- load this lane's 128-B segment (fully-owned cache line) ---
        float w[SEG];
        #pragma unroll
        for (int j = 0; j < SEG; j += 4) {
            float4 v = *(const float4*)(xr + lane * SEG + j);
            w[j] = v.x; w[j + 1] = v.y; w[j + 2] = v.z; w[j + 3] = v.w;
        }

        const float x0    = xr[0];                   // wave-uniform broadcast load
        const float xlast = __shfl(w[SEG - 1], 63);  // x[2047] from lane 63
        if (lane == 0) w[0] = sl * xlast + cl * x0;  // t0 replaces x[0] at k=0

        // --- pass 1: lane-local affine map (U, M), processing j = 31..0 ---
        float U = 0.0f, M = 1.0f;
        #pragma unroll
        for (int j = SEG - 1; j >= 0; --j) {
            U = c[j] * w[j] - s[j] * U;
            M = -s[j] * M;
        }

        // --- Kogge-Stone suffix scan: S_l = F_l ∘ F_{l+1} ∘ ... ∘ F_63 ---
        #pragma unroll
        for (int d = 1; d < 64; d <<= 1) {
            float Uo = __shfl_down(U, d);
            float Mo = __shfl_down(M, d);
            if (lane + d < 64) {
                U = U + M * Uo;     // apply other (higher lanes) first
                M = M * Mo;
            }
        }
        // incoming carry for this lane: a_in(l) = S_{l+1}(x0); lane 63 gets x0
        float Un = __shfl_down(U, 1);
        float Mn = __shfl_down(M, 1);
        float a  = (lane == 63) ? x0 : (Un + Mn * x0);

        // --- pass 2: emit outputs in place; e(j) = y[32l + j + 1] ---
        float e31 = 0.0f;
        #pragma unroll
        for (int j = SEG - 1; j >= 0; --j) {
            float e = s[j] * w[j] + c[j] * a;
            a       = c[j] * w[j] - s[j] * a;
            if (j == SEG - 1) e31 = e;       // belongs to lane l+1 slot 0
            else              w[j + 1] = e;  // slot j+1 of this lane
        }
        // slot 0: lane l takes lane l-1's first emission; lane 0's slot 0 = y[0] = final carry
        float prev = __shfl_up(e31, 1);
        w[0] = (lane == 0) ? a : prev;       // lane 63's e31 (= t0) is discarded

        // --- store this lane's fully-written 128-B line ---
        #pragma unroll
        for (int j = 0; j < SEG; j += 4) {
            *(float4*)(yr + lane * SEG + j) = make_float4(w[j], w[j + 1], w[j + 2], w[j + 3]);
        }
    }
}

extern "C" void kernel_launch(void* const* d_in, const int* in_sizes, int n_in,
                              void* d_out, int out_size, void* d_ws, size_t ws_size,
                              hipStream_t stream) {
    const float* x      = (const float*)d_in[0];
    const float* angles = (const float*)d_in[1];
    float* y            = (float*)d_out;

    const int B = in_sizes[0] / NN;                      // rows (16384)
    const int total_waves = (B + ROWS_PER_WAVE - 1) / ROWS_PER_WAVE;
    const int blocks = (total_waves + WPB - 1) / WPB;    // 1024 blocks x 256 threads
    hipLaunchKernelGGL(ring_givens_scan_kernel, dim3(blocks), dim3(256), 0, stream,
                       x, angles, y, B);
}